// Round 5
// baseline (9561.033 us; speedup 1.0000x reference)
//
#include <hip/hip_runtime.h>
#include <math.h>

// Problem constants
#define TT 512
#define BB 64
#define EE 300
#define HD 256
#define KK 20
#define NG 1024   // gate rows per direction (4*HD)

// ============================================================
// K0: transpose W_hh[1024][256] -> WT[256][1024], both directions.
// One-time prep so lstm's gate-parallel lanes load W coalesced.
// ============================================================
__global__ __launch_bounds__(256) void wtr_kernel(
    const float* __restrict__ Wf_hh, const float* __restrict__ Wb_hh,
    float* __restrict__ WTf, float* __restrict__ WTb)
{
    __shared__ float tile[64][65];
    const int dir = blockIdx.z;
    const int g0 = blockIdx.x * 64;   // 16
    const int k0 = blockIdx.y * 64;   // 4
    const float* W  = dir ? Wb_hh : Wf_hh;
    float*       WT = dir ? WTb : WTf;
    const int lx = threadIdx.x & 63, ly = threadIdx.x >> 6;
    for (int rr = ly; rr < 64; rr += 4)
        tile[rr][lx] = W[(size_t)(g0 + rr) * HD + k0 + lx];
    __syncthreads();
    for (int rr = ly; rr < 64; rr += 4)
        WT[(size_t)(k0 + rr) * NG + g0 + lx] = tile[lx][rr];
}

// ============================================================
// K1: fused embedding-gather + input projection GEMM (fp32)
// grid (CH, 32): x = step slot, y<16 fwd gate-block, y>=16 bwd.
// NEW layout: P[slot][row(64)][gate(1024)]  (gate innermost).
// ============================================================
__global__ __launch_bounds__(256) void proj_kernel(
    const int* __restrict__ sentence, const float* __restrict__ embed,
    const float* __restrict__ Wf_ih, const float* __restrict__ bf,
    const float* __restrict__ Wb_ih, const float* __restrict__ bb,
    float* __restrict__ Pf, float* __restrict__ Pb, int t0f, int t0b)
{
    __shared__ float As[32][BB];   // [k][b]
    __shared__ float Ws[32][64];   // [k][gate-local]
    const int s   = blockIdx.x;
    const int gb  = blockIdx.y;           // 0..31
    const int dir = gb >> 4;
    const int g0  = (gb & 15) * 64;       // gate base within direction
    const int tg  = dir ? (t0b + s) : (t0f + s);
    const int tid = threadIdx.x;
    const int tx = tid & 15, ty = tid >> 4;

    const int lrow = tid >> 2;            // 0..63 loader row
    const int kq   = tid & 3;
    const int word = sentence[lrow * TT + tg];
    const float* arow = embed + (size_t)word * EE;
    const float* Wih  = dir ? Wb_ih : Wf_ih;
    const float* bias = dir ? bb : bf;
    const float* wrow = Wih + (size_t)(g0 + lrow) * EE;

    float acc[4][4] = {};
    for (int k0 = 0; k0 < EE; k0 += 32) {
        __syncthreads();
        #pragma unroll
        for (int u = 0; u < 8; ++u) {
            const int k  = kq * 8 + u;
            const int kk = k0 + k;
            const bool ok = (kk < EE);
            As[k][lrow] = ok ? arow[kk] : 0.f;
            Ws[k][lrow] = ok ? wrow[kk] : 0.f;
        }
        __syncthreads();
        #pragma unroll
        for (int k = 0; k < 32; ++k) {
            const float4 a = *(const float4*)&As[k][ty * 4];
            const float4 w = *(const float4*)&Ws[k][tx * 4];
            acc[0][0] += a.x*w.x; acc[0][1] += a.x*w.y; acc[0][2] += a.x*w.z; acc[0][3] += a.x*w.w;
            acc[1][0] += a.y*w.x; acc[1][1] += a.y*w.y; acc[1][2] += a.y*w.z; acc[1][3] += a.y*w.w;
            acc[2][0] += a.z*w.x; acc[2][1] += a.z*w.y; acc[2][2] += a.z*w.z; acc[2][3] += a.z*w.w;
            acc[3][0] += a.w*w.x; acc[3][1] += a.w*w.y; acc[3][2] += a.w*w.z; acc[3][3] += a.w*w.w;
        }
    }
    // epilogue: P[s][r][g], r = ty*4+i, g = g0 + tx*4 + j
    float* Pd = (dir ? Pb : Pf) + (size_t)s * BB * NG;
    const float4 bv = *(const float4*)&bias[g0 + tx * 4];
    #pragma unroll
    for (int i = 0; i < 4; ++i) {
        float4 v;
        v.x = acc[i][0] + bv.x; v.y = acc[i][1] + bv.y;
        v.z = acc[i][2] + bv.z; v.w = acc[i][3] + bv.w;
        *(float4*)(Pd + (size_t)(ty * 4 + i) * NG + g0 + tx * 4) = v;
    }
}

// ============================================================
// K2: row-partitioned bidirectional LSTM — NO inter-block sync.
// 64 blocks × 512 threads: blk&1 = dir (dirs on alternate XCDs),
// blk>>1 = row pair. Each block owns 2 batch rows × all 256 h-dims;
// h lives in LDS, c in registers; only __syncthreads() per step.
// Cost/step/block: 524288 MACs (4096 cyc VALU) + 1 MB WT from L2.
// ============================================================
__global__ __launch_bounds__(512) void lstm_kernel(
    const float* __restrict__ Pf, const float* __restrict__ Pb,
    const float* __restrict__ WTf, const float* __restrict__ WTb,
    const int* __restrict__ lengths,
    float* __restrict__ HF, float* __restrict__ HB,
    float* __restrict__ state,     // [64 blocks][1024]: c[256][2] then h[256][2]
    int step0, int nsteps)
{
    __shared__ float hbuf[HD * 2];    // h[k][r] 2 KB
    __shared__ float gbuf[2][NG];     // gates[r][g] 8 KB
    const int blk  = blockIdx.x;
    const int dir  = blk & 1;
    const int pair = blk >> 1;        // 0..31
    const int r0   = pair * 2;
    const int tid  = threadIdx.x;     // 0..511
    const int g0   = tid * 2;         // this thread's two gate rows

    const float* WT = dir ? WTb : WTf;
    const float* P  = dir ? Pb : Pf;
    float* Hout = dir ? HB : HF;
    float* st = state + (size_t)blk * 1024;
    const int len0 = lengths[r0], len1 = lengths[r0 + 1];

    float c0 = 0.f, c1 = 0.f;
    if (tid < HD) {
        c0 = st[tid * 2 + 0];
        c1 = st[tid * 2 + 1];
        hbuf[tid * 2 + 0] = st[512 + tid * 2 + 0];
        hbuf[tid * 2 + 1] = st[512 + tid * 2 + 1];
    }
    __syncthreads();

    for (int u = 0; u < nsteps; ++u) {
        const int gs   = step0 + u;
        const int p    = dir ? (TT - 1 - gs) : gs;
        const int slot = dir ? (nsteps - 1 - u) : u;

        // P additive terms (independent of h — loads overlap the k-loop)
        const float* Pp = P + (size_t)slot * BB * NG;
        const float2 pr0 = *(const float2*)&Pp[(size_t)r0 * NG + g0];
        const float2 pr1 = *(const float2*)&Pp[(size_t)(r0 + 1) * NG + g0];

        // GEMV: acc[gate][row] over k; WT coalesced over gates, h broadcast
        float a00 = 0.f, a01 = 0.f, a10 = 0.f, a11 = 0.f;
        #pragma unroll 8
        for (int k = 0; k < HD; k += 2) {
            const float4 h2 = *(const float4*)&hbuf[k * 2];   // h[k][0..1],h[k+1][0..1]
            const float2 w0 = *(const float2*)&WT[(size_t)k * NG + g0];
            const float2 w1 = *(const float2*)&WT[(size_t)(k + 1) * NG + g0];
            a00 = fmaf(w0.x, h2.x, a00); a01 = fmaf(w0.y, h2.x, a01);
            a10 = fmaf(w0.x, h2.y, a10); a11 = fmaf(w0.y, h2.y, a11);
            a00 = fmaf(w1.x, h2.z, a00); a01 = fmaf(w1.y, h2.z, a01);
            a10 = fmaf(w1.x, h2.w, a10); a11 = fmaf(w1.y, h2.w, a11);
        }
        gbuf[0][g0] = a00 + pr0.x; gbuf[0][g0 + 1] = a01 + pr0.y;
        gbuf[1][g0] = a10 + pr1.x; gbuf[1][g0 + 1] = a11 + pr1.y;
        __syncthreads();   // all hbuf reads + gbuf writes complete

        if (tid < HD) {
            const int d = tid;
            const float i0 = gbuf[0][d],       i1 = gbuf[1][d];
            const float f0 = gbuf[0][256 + d], f1 = gbuf[1][256 + d];
            const float q0 = gbuf[0][512 + d], q1 = gbuf[1][512 + d];
            const float o0 = gbuf[0][768 + d], o1 = gbuf[1][768 + d];

            const float ig0 = 1.f / (1.f + expf(-i0));
            const float fg0 = 1.f / (1.f + expf(-f0));
            const float og0 = 1.f / (1.f + expf(-o0));
            const float gt0 = tanhf(q0);
            float cn0 = fg0 * c0 + ig0 * gt0;
            float hn0 = og0 * tanhf(cn0);

            const float ig1 = 1.f / (1.f + expf(-i1));
            const float fg1 = 1.f / (1.f + expf(-f1));
            const float og1 = 1.f / (1.f + expf(-o1));
            const float gt1 = tanhf(q1);
            float cn1 = fg1 * c1 + ig1 * gt1;
            float hn1 = og1 * tanhf(cn1);

            if (dir) {   // bwd: rows inactive until p < len (padded-t emissions unused)
                const bool v0 = (p < len0), v1 = (p < len1);
                c0 = v0 ? cn0 : c0;  hn0 = v0 ? hn0 : 0.f;
                c1 = v1 ? cn1 : c1;  hn1 = v1 ? hn1 : 0.f;
            } else {
                c0 = cn0; c1 = cn1;
            }
            hbuf[d * 2 + 0] = hn0;
            hbuf[d * 2 + 1] = hn1;
            float2 hv; hv.x = hn0; hv.y = hn1;
            *(float2*)&Hout[((size_t)p * HD + d) * BB + r0] = hv;  // [t][d][r] layout
        }
        __syncthreads();   // hbuf stable for next k-loop
    }

    if (tid < HD) {
        st[tid * 2 + 0] = c0;
        st[tid * 2 + 1] = c1;
        st[512 + tid * 2 + 0] = hbuf[tid * 2 + 0];
        st[512 + tid * 2 + 1] = hbuf[tid * 2 + 1];
    }
}

// ============================================================
// K3: emissions = [hf|hb] @ W_out^T + b_out -> emis[t][b][20]
// ============================================================
__global__ __launch_bounds__(256) void emis_kernel(
    const float* __restrict__ HF, const float* __restrict__ HB,
    const float* __restrict__ W_out, const float* __restrict__ b_out,
    float* __restrict__ emis)
{
    const int t = blockIdx.x;
    const int b = threadIdx.x & 63;
    int jg = threadIdx.x >> 6;
    jg = __builtin_amdgcn_readfirstlane(jg);

    float acc[5];
    #pragma unroll
    for (int u = 0; u < 5; ++u) acc[u] = b_out[jg + 4 * u];

    const float* hf = HF + (size_t)t * HD * BB + b;
    const float* hb = HB + (size_t)t * HD * BB + b;
    for (int k = 0; k < HD; ++k) {
        const float hv = hf[(size_t)k * BB];
        #pragma unroll
        for (int u = 0; u < 5; ++u)
            acc[u] = fmaf(hv, W_out[(size_t)(jg + 4 * u) * 512 + k], acc[u]);
    }
    for (int k = 0; k < HD; ++k) {
        const float hv = hb[(size_t)k * BB];
        #pragma unroll
        for (int u = 0; u < 5; ++u)
            acc[u] = fmaf(hv, W_out[(size_t)(jg + 4 * u) * 512 + HD + k], acc[u]);
    }
    #pragma unroll
    for (int u = 0; u < 5; ++u)
        emis[((size_t)t * BB + b) * KK + jg + 4 * u] = acc[u];
}

// ============================================================
// K4: Viterbi per batch row; exact first-max argmax; bp in LDS.
// ============================================================
__global__ __launch_bounds__(64) void viterbi_kernel(
    const float* __restrict__ emis, const int* __restrict__ lengths,
    const float* __restrict__ trans, const int* __restrict__ stop_id_p,
    float* __restrict__ out)
{
    __shared__ float tr[KK * KK];
    __shared__ float delta[KK], nd[KK];
    __shared__ unsigned char bp[TT][KK];
    const int b = blockIdx.x;
    const int tid = threadIdx.x;
    for (int i = tid; i < KK * KK; i += 64) tr[i] = trans[i];
    if (tid < KK) delta[tid] = 0.f;
    const int len = lengths[b];
    __syncthreads();

    for (int t = 0; t < TT; ++t) {
        if (tid < KK) {
            if (t < len) {
                float best = delta[0] + tr[tid * KK + 0];
                int am = 0;
                for (int p2 = 1; p2 < KK; ++p2) {
                    const float v = delta[p2] + tr[tid * KK + p2];
                    if (v > best) { best = v; am = p2; }
                }
                nd[tid] = best + emis[((size_t)t * BB + b) * KK + tid];
                bp[t][tid] = (unsigned char)am;
            } else {
                nd[tid] = delta[tid];
                bp[t][tid] = (unsigned char)tid;
            }
        }
        __syncthreads();
        if (tid < KK) delta[tid] = nd[tid];
        __syncthreads();
    }

    if (tid == 0) {
        const int stop_id = *stop_id_p;
        float best = delta[0] + tr[stop_id * KK + 0];
        int bl = 0;
        for (int j = 1; j < KK; ++j) {
            const float v = delta[j] + tr[stop_id * KK + j];
            if (v > best) { best = v; bl = j; }
        }
        out[b] = best;
        float* pout = out + BB + (size_t)b * (TT + 1);
        pout[TT] = (float)bl;
        int tag = bl;
        for (int t = TT - 1; t >= 0; --t) {
            tag = bp[t][tag];
            pout[t] = (float)tag;
        }
    }
}

// ============================================================
extern "C" void kernel_launch(void* const* d_in, const int* in_sizes, int n_in,
                              void* d_out, int out_size, void* d_ws, size_t ws_size,
                              hipStream_t stream) {
    const int*   sentence = (const int*)d_in[0];
    const int*   lengths  = (const int*)d_in[1];
    const int*   stop_id  = (const int*)d_in[3];
    const float* embed    = (const float*)d_in[4];
    const float* Wf_ih    = (const float*)d_in[5];
    const float* Wf_hh    = (const float*)d_in[6];
    const float* bf       = (const float*)d_in[7];
    const float* Wb_ih    = (const float*)d_in[8];
    const float* Wb_hh    = (const float*)d_in[9];
    const float* bb       = (const float*)d_in[10];
    const float* W_out    = (const float*)d_in[11];
    const float* b_out    = (const float*)d_in[12];
    const float* trans    = (const float*)d_in[13];
    float* out = (float*)d_out;

    const size_t hf_elems    = (size_t)TT * HD * BB;       // 8.39M
    const size_t emis_elems  = (size_t)TT * BB * KK;
    const size_t wt_elems    = (size_t)2 * HD * NG;        // 524288
    const size_t state_elems = (size_t)64 * 1024;          // 65536
    const size_t fixed_bytes = (2 * hf_elems + emis_elems + wt_elems + state_elems) * 4;

    int CH = 0;
    const int cands[6] = {256, 128, 64, 32, 16, 8};
    for (int i = 0; i < 6; ++i) {
        const size_t need = fixed_bytes + 2ull * cands[i] * BB * NG * 4;
        if (need <= ws_size) { CH = cands[i]; break; }
    }
    if (CH == 0) return;   // ws too small: fail loudly, don't fault

    float* WTf   = (float*)d_ws;
    float* WTb   = WTf + (size_t)HD * NG;
    float* Pf    = WTb + (size_t)HD * NG;
    float* Pb    = Pf + (size_t)CH * BB * NG;
    float* HF    = Pb + (size_t)CH * BB * NG;
    float* HB    = HF + hf_elems;
    float* emis  = HB + hf_elems;
    float* state = emis + emis_elems;

    hipMemsetAsync(state, 0, state_elems * 4, stream);   // zero h,c persistent state
    wtr_kernel<<<dim3(16, 4, 2), 256, 0, stream>>>(Wf_hh, Wb_hh, WTf, WTb);

    const int nch = TT / CH;
    for (int c = 0; c < nch; ++c) {
        const int t0f = c * CH;
        const int t0b = TT - (c + 1) * CH;
        proj_kernel<<<dim3(CH, 32), 256, 0, stream>>>(
            sentence, embed, Wf_ih, bf, Wb_ih, bb, Pf, Pb, t0f, t0b);
        lstm_kernel<<<dim3(64), 512, 0, stream>>>(
            Pf, Pb, WTf, WTb, lengths, HF, HB, state, c * CH, CH);
    }
    emis_kernel<<<dim3(TT), 256, 0, stream>>>(HF, HB, W_out, b_out, emis);
    viterbi_kernel<<<dim3(BB), 64, 0, stream>>>(emis, lengths, trans, stop_id, out);
}

// Round 6
// 9517.609 us; speedup vs baseline: 1.0046x; 1.0046x over previous
//
#include <hip/hip_runtime.h>
#include <math.h>

// Problem constants
#define TT 512
#define BB 64
#define EE 300
#define HD 256
#define KK 20
#define NG 1024   // gate rows per direction (4*HD)

// ============================================================
// K0: transpose W_hh[1024][256] -> WT[256][1024], both directions.
// ============================================================
__global__ __launch_bounds__(256) void wtr_kernel(
    const float* __restrict__ Wf_hh, const float* __restrict__ Wb_hh,
    float* __restrict__ WTf, float* __restrict__ WTb)
{
    __shared__ float tile[64][65];
    const int dir = blockIdx.z;
    const int g0 = blockIdx.x * 64;   // 16
    const int k0 = blockIdx.y * 64;   // 4
    const float* W  = dir ? Wb_hh : Wf_hh;
    float*       WT = dir ? WTb : WTf;
    const int lx = threadIdx.x & 63, ly = threadIdx.x >> 6;
    for (int rr = ly; rr < 64; rr += 4)
        tile[rr][lx] = W[(size_t)(g0 + rr) * HD + k0 + lx];
    __syncthreads();
    for (int rr = ly; rr < 64; rr += 4)
        WT[(size_t)(k0 + rr) * NG + g0 + lx] = tile[lx][rr];
}

// ============================================================
// K1: fused embedding-gather + input projection GEMM (fp32)
// P layout: [slot][row(64)][gate(1024)] (gate innermost).
// ============================================================
__global__ __launch_bounds__(256) void proj_kernel(
    const int* __restrict__ sentence, const float* __restrict__ embed,
    const float* __restrict__ Wf_ih, const float* __restrict__ bf,
    const float* __restrict__ Wb_ih, const float* __restrict__ bb,
    float* __restrict__ Pf, float* __restrict__ Pb, int t0f, int t0b)
{
    __shared__ float As[32][BB];   // [k][b]
    __shared__ float Ws[32][64];   // [k][gate-local]
    const int s   = blockIdx.x;
    const int gb  = blockIdx.y;           // 0..31
    const int dir = gb >> 4;
    const int g0  = (gb & 15) * 64;
    const int tg  = dir ? (t0b + s) : (t0f + s);
    const int tid = threadIdx.x;
    const int tx = tid & 15, ty = tid >> 4;

    const int lrow = tid >> 2;
    const int kq   = tid & 3;
    const int word = sentence[lrow * TT + tg];
    const float* arow = embed + (size_t)word * EE;
    const float* Wih  = dir ? Wb_ih : Wf_ih;
    const float* bias = dir ? bb : bf;
    const float* wrow = Wih + (size_t)(g0 + lrow) * EE;

    float acc[4][4] = {};
    for (int k0 = 0; k0 < EE; k0 += 32) {
        __syncthreads();
        #pragma unroll
        for (int u = 0; u < 8; ++u) {
            const int k  = kq * 8 + u;
            const int kk = k0 + k;
            const bool ok = (kk < EE);
            As[k][lrow] = ok ? arow[kk] : 0.f;
            Ws[k][lrow] = ok ? wrow[kk] : 0.f;
        }
        __syncthreads();
        #pragma unroll
        for (int k = 0; k < 32; ++k) {
            const float4 a = *(const float4*)&As[k][ty * 4];
            const float4 w = *(const float4*)&Ws[k][tx * 4];
            acc[0][0] += a.x*w.x; acc[0][1] += a.x*w.y; acc[0][2] += a.x*w.z; acc[0][3] += a.x*w.w;
            acc[1][0] += a.y*w.x; acc[1][1] += a.y*w.y; acc[1][2] += a.y*w.z; acc[1][3] += a.y*w.w;
            acc[2][0] += a.z*w.x; acc[2][1] += a.z*w.y; acc[2][2] += a.z*w.z; acc[2][3] += a.z*w.w;
            acc[3][0] += a.w*w.x; acc[3][1] += a.w*w.y; acc[3][2] += a.w*w.z; acc[3][3] += a.w*w.w;
        }
    }
    float* Pd = (dir ? Pb : Pf) + (size_t)s * BB * NG;
    const float4 bv = *(const float4*)&bias[g0 + tx * 4];
    #pragma unroll
    for (int i = 0; i < 4; ++i) {
        float4 v;
        v.x = acc[i][0] + bv.x; v.y = acc[i][1] + bv.y;
        v.z = acc[i][2] + bv.z; v.w = acc[i][3] + bv.w;
        *(float4*)(Pd + (size_t)(ty * 4 + i) * NG + g0 + tx * 4) = v;
    }
}

// ============================================================
// K2: row-partitioned bidirectional LSTM — NO inter-block sync.
// 64 blocks × 512 threads: blk&1 = dir, blk>>1 = row pair.
// h in LDS, c in regs; 2 __syncthreads()/step only.
// Fixes vs R5: H layout [t][r][d] (contiguous per-block stores, cheap
// vmcnt drain at the barrier) and cell phase across all 8 waves.
// ============================================================
__global__ __launch_bounds__(512) void lstm_kernel(
    const float* __restrict__ Pf, const float* __restrict__ Pb,
    const float* __restrict__ WTf, const float* __restrict__ WTb,
    const int* __restrict__ lengths,
    float* __restrict__ HF, float* __restrict__ HB,
    float* __restrict__ state,     // [64 blocks][1024]: c[2][256] then h[2][256]
    int step0, int nsteps)
{
    __shared__ __align__(16) float hbuf[HD * 2];   // h[k][row] 2 KB
    __shared__ float gbuf[2][NG];                  // gates[row][g] 8 KB
    const int blk  = blockIdx.x;
    const int dir  = blk & 1;
    const int pair = blk >> 1;        // 0..31
    const int r0   = pair * 2;
    const int tid  = threadIdx.x;     // 0..511
    const int g0   = tid * 2;         // this thread's two gate rows
    const int row  = tid >> 8;        // cell-phase row (0/1)
    const int d    = tid & 255;       // cell-phase h-dim

    const float* WT = dir ? WTb : WTf;
    const float* P  = dir ? Pb : Pf;
    float* Hout = dir ? HB : HF;
    float* st = state + (size_t)blk * 1024;
    const int lenr = lengths[r0 + row];

    // per-thread cell state for (row, d); h into LDS
    float cc = st[row * 256 + d];
    hbuf[d * 2 + row] = st[512 + row * 256 + d];
    __syncthreads();

    for (int u = 0; u < nsteps; ++u) {
        const int gs   = step0 + u;
        const int p    = dir ? (TT - 1 - gs) : gs;
        const int slot = dir ? (nsteps - 1 - u) : u;

        // P additive terms (h-independent; overlap the k-loop)
        const float* Pp = P + (size_t)slot * BB * NG;
        const float2 pr0 = *(const float2*)&Pp[(size_t)r0 * NG + g0];
        const float2 pr1 = *(const float2*)&Pp[(size_t)(r0 + 1) * NG + g0];

        // GEMV: acc[gate][row] over k; WT coalesced over gates, h broadcast
        float a00 = 0.f, a01 = 0.f, a10 = 0.f, a11 = 0.f;
        #pragma unroll 8
        for (int k = 0; k < HD; k += 2) {
            const float4 h2 = *(const float4*)&hbuf[k * 2];
            const float2 w0 = *(const float2*)&WT[(size_t)k * NG + g0];
            const float2 w1 = *(const float2*)&WT[(size_t)(k + 1) * NG + g0];
            a00 = fmaf(w0.x, h2.x, a00); a01 = fmaf(w0.y, h2.x, a01);
            a10 = fmaf(w0.x, h2.y, a10); a11 = fmaf(w0.y, h2.y, a11);
            a00 = fmaf(w1.x, h2.z, a00); a01 = fmaf(w1.y, h2.z, a01);
            a10 = fmaf(w1.x, h2.w, a10); a11 = fmaf(w1.y, h2.w, a11);
        }
        gbuf[0][g0] = a00 + pr0.x; gbuf[0][g0 + 1] = a01 + pr0.y;
        gbuf[1][g0] = a10 + pr1.x; gbuf[1][g0 + 1] = a11 + pr1.y;
        __syncthreads();   // hbuf reads + gbuf writes complete

        // cell phase: all 8 waves, thread = (row, d)
        {
            const float iv = gbuf[row][d];
            const float fv = gbuf[row][256 + d];
            const float qv = gbuf[row][512 + d];
            const float ov = gbuf[row][768 + d];

            const float ig = 1.f / (1.f + expf(-iv));
            const float fg = 1.f / (1.f + expf(-fv));
            const float og = 1.f / (1.f + expf(-ov));
            const float gt = tanhf(qv);
            float cn = fg * cc + ig * gt;
            float hn = og * tanhf(cn);
            if (dir) {   // bwd: row inactive until p < len
                const bool v = (p < lenr);
                cc = v ? cn : cc;
                hn = v ? hn : 0.f;
            } else {
                cc = cn;
            }
            hbuf[d * 2 + row] = hn;
            // [t][r][d]: per-wave 256B contiguous store
            Hout[((size_t)p * BB + r0 + row) * HD + d] = hn;
        }
        __syncthreads();   // hbuf stable for next k-loop
    }

    st[row * 256 + d] = cc;
    st[512 + row * 256 + d] = hbuf[d * 2 + row];
}

// ============================================================
// K3: emissions = [hf|hb] @ W_out^T + b_out -> emis[t][b][20]
// H layout [t][r][d]. Block per t; thread = (r = tid>>2, jg = tid&3),
// jg covers outputs {jg, jg+4, ..., jg+16}.
// ============================================================
__global__ __launch_bounds__(256) void emis_kernel(
    const float* __restrict__ HF, const float* __restrict__ HB,
    const float* __restrict__ W_out, const float* __restrict__ b_out,
    float* __restrict__ emis)
{
    const int t  = blockIdx.x;
    const int r  = threadIdx.x >> 2;
    const int jg = threadIdx.x & 3;

    float acc[5];
    #pragma unroll
    for (int u = 0; u < 5; ++u) acc[u] = b_out[jg + 4 * u];

    const float* hf = HF + ((size_t)t * BB + r) * HD;
    const float* hb = HB + ((size_t)t * BB + r) * HD;
    for (int k = 0; k < HD; k += 4) {
        const float4 hv = *(const float4*)&hf[k];
        #pragma unroll
        for (int u = 0; u < 5; ++u) {
            const float* wr = &W_out[(size_t)(jg + 4 * u) * 512 + k];
            acc[u] = fmaf(hv.x, wr[0], acc[u]);
            acc[u] = fmaf(hv.y, wr[1], acc[u]);
            acc[u] = fmaf(hv.z, wr[2], acc[u]);
            acc[u] = fmaf(hv.w, wr[3], acc[u]);
        }
    }
    for (int k = 0; k < HD; k += 4) {
        const float4 hv = *(const float4*)&hb[k];
        #pragma unroll
        for (int u = 0; u < 5; ++u) {
            const float* wr = &W_out[(size_t)(jg + 4 * u) * 512 + HD + k];
            acc[u] = fmaf(hv.x, wr[0], acc[u]);
            acc[u] = fmaf(hv.y, wr[1], acc[u]);
            acc[u] = fmaf(hv.z, wr[2], acc[u]);
            acc[u] = fmaf(hv.w, wr[3], acc[u]);
        }
    }
    #pragma unroll
    for (int u = 0; u < 5; ++u)
        emis[((size_t)t * BB + r) * KK + jg + 4 * u] = acc[u];
}

// ============================================================
// K4: Viterbi per batch row; exact first-max argmax; bp in LDS.
// ============================================================
__global__ __launch_bounds__(64) void viterbi_kernel(
    const float* __restrict__ emis, const int* __restrict__ lengths,
    const float* __restrict__ trans, const int* __restrict__ stop_id_p,
    float* __restrict__ out)
{
    __shared__ float tr[KK * KK];
    __shared__ float delta[KK], nd[KK];
    __shared__ unsigned char bp[TT][KK];
    const int b = blockIdx.x;
    const int tid = threadIdx.x;
    for (int i = tid; i < KK * KK; i += 64) tr[i] = trans[i];
    if (tid < KK) delta[tid] = 0.f;
    const int len = lengths[b];
    __syncthreads();

    for (int t = 0; t < TT; ++t) {
        if (tid < KK) {
            if (t < len) {
                float best = delta[0] + tr[tid * KK + 0];
                int am = 0;
                for (int p2 = 1; p2 < KK; ++p2) {
                    const float v = delta[p2] + tr[tid * KK + p2];
                    if (v > best) { best = v; am = p2; }
                }
                nd[tid] = best + emis[((size_t)t * BB + b) * KK + tid];
                bp[t][tid] = (unsigned char)am;
            } else {
                nd[tid] = delta[tid];
                bp[t][tid] = (unsigned char)tid;
            }
        }
        __syncthreads();
        if (tid < KK) delta[tid] = nd[tid];
        __syncthreads();
    }

    if (tid == 0) {
        const int stop_id = *stop_id_p;
        float best = delta[0] + tr[stop_id * KK + 0];
        int bl = 0;
        for (int j = 1; j < KK; ++j) {
            const float v = delta[j] + tr[stop_id * KK + j];
            if (v > best) { best = v; bl = j; }
        }
        out[b] = best;
        float* pout = out + BB + (size_t)b * (TT + 1);
        pout[TT] = (float)bl;
        int tag = bl;
        for (int t = TT - 1; t >= 0; --t) {
            tag = bp[t][tag];
            pout[t] = (float)tag;
        }
    }
}

// ============================================================
extern "C" void kernel_launch(void* const* d_in, const int* in_sizes, int n_in,
                              void* d_out, int out_size, void* d_ws, size_t ws_size,
                              hipStream_t stream) {
    const int*   sentence = (const int*)d_in[0];
    const int*   lengths  = (const int*)d_in[1];
    const int*   stop_id  = (const int*)d_in[3];
    const float* embed    = (const float*)d_in[4];
    const float* Wf_ih    = (const float*)d_in[5];
    const float* Wf_hh    = (const float*)d_in[6];
    const float* bf       = (const float*)d_in[7];
    const float* Wb_ih    = (const float*)d_in[8];
    const float* Wb_hh    = (const float*)d_in[9];
    const float* bb       = (const float*)d_in[10];
    const float* W_out    = (const float*)d_in[11];
    const float* b_out    = (const float*)d_in[12];
    const float* trans    = (const float*)d_in[13];
    float* out = (float*)d_out;

    const size_t hf_elems    = (size_t)TT * HD * BB;
    const size_t emis_elems  = (size_t)TT * BB * KK;
    const size_t wt_elems    = (size_t)2 * HD * NG;
    const size_t state_elems = (size_t)64 * 1024;
    const size_t fixed_bytes = (2 * hf_elems + emis_elems + wt_elems + state_elems) * 4;

    int CH = 0;
    const int cands[6] = {256, 128, 64, 32, 16, 8};
    for (int i = 0; i < 6; ++i) {
        const size_t need = fixed_bytes + 2ull * cands[i] * BB * NG * 4;
        if (need <= ws_size) { CH = cands[i]; break; }
    }
    if (CH == 0) return;

    float* WTf   = (float*)d_ws;
    float* WTb   = WTf + (size_t)HD * NG;
    float* Pf    = WTb + (size_t)HD * NG;
    float* Pb    = Pf + (size_t)CH * BB * NG;
    float* HF    = Pb + (size_t)CH * BB * NG;
    float* HB    = HF + hf_elems;
    float* emis  = HB + hf_elems;
    float* state = emis + emis_elems;

    hipMemsetAsync(state, 0, state_elems * 4, stream);
    wtr_kernel<<<dim3(16, 4, 2), 256, 0, stream>>>(Wf_hh, Wb_hh, WTf, WTb);

    const int nch = TT / CH;
    for (int c = 0; c < nch; ++c) {
        const int t0f = c * CH;
        const int t0b = TT - (c + 1) * CH;
        proj_kernel<<<dim3(CH, 32), 256, 0, stream>>>(
            sentence, embed, Wf_ih, bf, Wb_ih, bb, Pf, Pb, t0f, t0b);
        lstm_kernel<<<dim3(64), 512, 0, stream>>>(
            Pf, Pb, WTf, WTb, lengths, HF, HB, state, c * CH, CH);
    }
    emis_kernel<<<dim3(TT), 256, 0, stream>>>(HF, HB, W_out, b_out, emis);
    viterbi_kernel<<<dim3(BB), 64, 0, stream>>>(emis, lengths, trans, stop_id, out);
}